// Round 1
// baseline (110.023 us; speedup 1.0000x reference)
//
#include <hip/hip_runtime.h>
#include <cstddef>

using bf16x8  = __attribute__((ext_vector_type(8))) short;
using f32x4   = __attribute__((ext_vector_type(4))) float;
using ushort8 = __attribute__((ext_vector_type(8))) unsigned short;

#define GLL16(gp, lp) __builtin_amdgcn_global_load_lds( \
    (const __attribute__((address_space(1))) unsigned int*)(const void*)(gp), \
    (__attribute__((address_space(3))) unsigned int*)(void*)(lp), 16, 0, 0)

__device__ __forceinline__ float exp2_f(float x){ float r; asm("v_exp_f32 %0, %1" : "=v"(r) : "v"(x)); return r; }
__device__ __forceinline__ float rcp_f (float x){ float r; asm("v_rcp_f32 %0, %1" : "=v"(r) : "v"(x)); return r; }

__device__ __forceinline__ unsigned short f2bf(float f){
  unsigned int u = __float_as_uint(f);
  u = u + 0x7FFFu + ((u >> 16) & 1u);
  return (unsigned short)(u >> 16);
}

// problem sizes: B=8 Q=16 KV=2048 NQ=NK=NV=H=512
#define KEYS_N   8388608
#define QUERY_N  65536
#define W_N      524288
#define SCALE_2LOG2E 2.885390081777927f   // 2*log2(e): exp2(x*S) = exp(2x)

// workspace layout (bytes); total = 61,210,624
#define OFF_KEYS_BF   0u          // 16384x512 bf16
#define OFF_QUERY_BF  16777216u   // 128x512 bf16
#define OFF_WK_BF     16908288u   // 512x512 bf16
#define OFF_WQ_BF     17432576u   // 512x512 bf16
#define OFF_KPB       17956864u   // 16384x512 f32 (scaled k_part + bias)
#define OFF_QP        51511296u   // 128x512 f32 (scaled q_part)
#define OFF_E         51773440u   // 8x2048x16 f32 (logits -> scores in place)
#define OFF_PART      52822016u   // 8x32x16x512 f32 partial outputs

// ---------------- K1: f32 -> bf16 conversion (keys, query, W split) -------
__global__ __launch_bounds__(256) void k_convert(
    const float* __restrict__ query, const float* __restrict__ keys,
    const float* __restrict__ W,
    unsigned short* __restrict__ keys_bf, unsigned short* __restrict__ query_bf,
    unsigned short* __restrict__ wk_bf, unsigned short* __restrict__ wq_bf)
{
  int idx = (blockIdx.x * 256 + threadIdx.x) * 8;
  const float* src;
  unsigned short* dst;
  if (idx < KEYS_N) { src = keys + idx; dst = keys_bf + idx; }
  else if (idx < KEYS_N + QUERY_N) { int e = idx - KEYS_N; src = query + e; dst = query_bf + e; }
  else {
    int e = idx - (KEYS_N + QUERY_N);
    int h = e >> 10, c = e & 1023;             // W row-major [512][1024]
    src = W + e;
    dst = (c < 512) ? (wq_bf + h * 512 + c) : (wk_bf + h * 512 + (c - 512));
  }
  float4 a = *(const float4*)src;
  float4 b = *(const float4*)(src + 4);
  ushort8 o;
  o[0]=f2bf(a.x); o[1]=f2bf(a.y); o[2]=f2bf(a.z); o[3]=f2bf(a.w);
  o[4]=f2bf(b.x); o[5]=f2bf(b.y); o[6]=f2bf(b.z); o[7]=f2bf(b.w);
  *(ushort8*)dst = o;
}

// ---------------- K2: MFMA GEMM: kpb = S*(keys·Wk^T + bias), qp = S*(query·Wq^T)
// 128x128 tile, BK=64, 4 waves (2x2 of 64x64), double-buffered LDS,
// global_load_lds width 16. grid = (4 n-tiles, 129 m-tiles); y==128 -> query.
__global__ __launch_bounds__(256) void k_gemm(
    const unsigned short* __restrict__ keys_bf, const unsigned short* __restrict__ query_bf,
    const unsigned short* __restrict__ wk_bf, const unsigned short* __restrict__ wq_bf,
    const float* __restrict__ w_bias,
    float* __restrict__ kpb, float* __restrict__ qp)
{
  __shared__ short As[2][128 * 64];
  __shared__ short Bs[2][128 * 64];

  const int tid = threadIdx.x;
  const int l = tid & 63;
  const int w = tid >> 6;
  const int by = blockIdx.y;            // 0..128; 128 => query tile
  const bool isq = (by == 128);
  const int n0 = blockIdx.x * 128;

  const unsigned short* Aptr = isq ? query_bf : (keys_bf + (size_t)by * 128 * 512);
  const unsigned short* Bptr = (isq ? wq_bf : wk_bf) + (size_t)n0 * 512;

  const int eo_base = w * 2048 + l * 8;   // element offset in 128x64 tile

  f32x4 acc[4][4];
  #pragma unroll
  for (int i = 0; i < 4; ++i)
    #pragma unroll
    for (int j = 0; j < 4; ++j)
      acc[i][j] = (f32x4){0.f, 0.f, 0.f, 0.f};

  auto stage = [&](int buf, int kt) {
    const int k0 = kt * 64;
    #pragma unroll
    for (int r = 0; r < 4; ++r) {
      const int eo = eo_base + r * 512;
      const int row = eo >> 6;
      const int col = eo & 63;
      GLL16(Aptr + row * 512 + k0 + col, &As[buf][w * 2048 + r * 512]);
      GLL16(Bptr + row * 512 + k0 + col, &Bs[buf][w * 2048 + r * 512]);
    }
  };

  const int wm = w >> 1, wn = w & 1;
  const int fr = l & 15;          // m/n index within 16x16 fragment
  const int fg = l >> 4;          // k-group

  auto compute = [&](int buf) {
    #pragma unroll
    for (int ks = 0; ks < 2; ++ks) {
      bf16x8 af[4], bfv[4];
      #pragma unroll
      for (int i = 0; i < 4; ++i) {
        const int ar = wm * 64 + i * 16 + fr;
        af[i]  = *(const bf16x8*)&As[buf][ar * 64 + ks * 32 + fg * 8];
        const int br = wn * 64 + i * 16 + fr;
        bfv[i] = *(const bf16x8*)&Bs[buf][br * 64 + ks * 32 + fg * 8];
      }
      #pragma unroll
      for (int i = 0; i < 4; ++i)
        #pragma unroll
        for (int j = 0; j < 4; ++j)
          acc[i][j] = __builtin_amdgcn_mfma_f32_16x16x32_bf16(af[i], bfv[j], acc[i][j], 0, 0, 0);
    }
  };

  stage(0, 0);
  for (int kt = 0; kt < 8; ++kt) {
    __syncthreads();                       // buf[kt&1] staged (vmcnt drains)
    if (kt < 7) stage((kt + 1) & 1, kt + 1);
    compute(kt & 1);
  }

  // epilogue: C/D layout col=lane&15, row=(lane>>4)*4+reg  [m89-verified]
  #pragma unroll
  for (int j = 0; j < 4; ++j) {
    const int gh = n0 + wn * 64 + j * 16 + fr;
    const float bias = isq ? 0.f : w_bias[gh];
    #pragma unroll
    for (int i = 0; i < 4; ++i) {
      #pragma unroll
      for (int r = 0; r < 4; ++r) {
        const int gm = wm * 64 + i * 16 + fg * 4 + r;
        const float val = (acc[i][j][r] + bias) * SCALE_2LOG2E;
        if (isq) qp[gm * 512 + gh] = val;
        else     kpb[((size_t)by * 128 + gm) * 512 + gh] = val;
      }
    }
  }
}

// ---------------- K3: e'[b,k,q] = sum_h -2*v_h / (exp2(kpb+qp)+1) ----------
// (= sum_h v_h*tanh(k_part+q_part+bias) minus a (b,k,q)-constant -> softmax-invariant)
__global__ __launch_bounds__(256) void k_energy(
    const float* __restrict__ kpb, const float* __restrict__ qp,
    const float* __restrict__ vw, float* __restrict__ e)
{
  __shared__ float qlds[16 * 512];
  const int tid = threadIdx.x;
  const int b = blockIdx.x >> 9;          // 4 rows/block, 2048 rows/batch
  const float* qsrc = qp + b * (16 * 512);
  #pragma unroll
  for (int i = 0; i < 8; ++i) {
    const int o = tid * 4 + i * 1024;
    *(float4*)&qlds[o] = *(const float4*)&qsrc[o];
  }
  __syncthreads();

  const int l = tid & 63;
  const int r0 = blockIdx.x * 4 + (tid >> 6);   // global (b,k) row

  const float* kr = kpb + (size_t)r0 * 512 + l * 8;
  const float4 k0 = *(const float4*)kr;
  const float4 k1 = *(const float4*)(kr + 4);
  const float* vp = vw + l * 8;
  const float4 v0 = *(const float4*)vp;
  const float4 v1 = *(const float4*)(vp + 4);
  const float m0 = -2.f*v0.x, m1 = -2.f*v0.y, m2 = -2.f*v0.z, m3 = -2.f*v0.w;
  const float m4 = -2.f*v1.x, m5 = -2.f*v1.y, m6 = -2.f*v1.z, m7 = -2.f*v1.w;

  float acc[16];
  #pragma unroll
  for (int q = 0; q < 16; ++q) {
    const float* qr = &qlds[q * 512 + l * 8];
    const float4 qa = *(const float4*)qr;
    const float4 qb = *(const float4*)(qr + 4);
    float s = 0.f;
    s += m0 * rcp_f(exp2_f(k0.x + qa.x) + 1.f);
    s += m1 * rcp_f(exp2_f(k0.y + qa.y) + 1.f);
    s += m2 * rcp_f(exp2_f(k0.z + qa.z) + 1.f);
    s += m3 * rcp_f(exp2_f(k0.w + qa.w) + 1.f);
    s += m4 * rcp_f(exp2_f(k1.x + qb.x) + 1.f);
    s += m5 * rcp_f(exp2_f(k1.y + qb.y) + 1.f);
    s += m6 * rcp_f(exp2_f(k1.z + qb.z) + 1.f);
    s += m7 * rcp_f(exp2_f(k1.w + qb.w) + 1.f);
    acc[q] = s;
  }
  #pragma unroll
  for (int q = 0; q < 16; ++q) {
    float s = acc[q];
    #pragma unroll
    for (int msk = 1; msk < 64; msk <<= 1) s += __shfl_xor(s, msk, 64);
    acc[q] = s;
  }
  if (l == 0) {
    float* ep = e + r0 * 16;
    #pragma unroll
    for (int q = 0; q < 16; ++q) ep[q] = acc[q];
  }
}

// ---------------- K4: softmax over k (in place), one block per (b,q) -------
__global__ __launch_bounds__(256) void k_softmax(float* __restrict__ e)
{
  const int b = blockIdx.x >> 4, q = blockIdx.x & 15;
  float* base = e + b * 2048 * 16 + q;    // stride 16 over k
  const int tid = threadIdx.x;
  __shared__ float redm[4], reds[4];

  float vals[8];
  float mx = -1e30f;
  #pragma unroll
  for (int i = 0; i < 8; ++i) { vals[i] = base[(tid + i * 256) * 16]; mx = fmaxf(mx, vals[i]); }
  #pragma unroll
  for (int msk = 1; msk < 64; msk <<= 1) mx = fmaxf(mx, __shfl_xor(mx, msk, 64));
  if ((tid & 63) == 0) redm[tid >> 6] = mx;
  __syncthreads();
  mx = fmaxf(fmaxf(redm[0], redm[1]), fmaxf(redm[2], redm[3]));

  float ex[8], sum = 0.f;
  #pragma unroll
  for (int i = 0; i < 8; ++i) { ex[i] = __expf(vals[i] - mx); sum += ex[i]; }
  #pragma unroll
  for (int msk = 1; msk < 64; msk <<= 1) sum += __shfl_xor(sum, msk, 64);
  if ((tid & 63) == 0) reds[tid >> 6] = sum;
  __syncthreads();
  sum = reds[0] + reds[1] + reds[2] + reds[3];
  const float r = 1.f / sum;
  #pragma unroll
  for (int i = 0; i < 8; ++i) base[(tid + i * 256) * 16] = ex[i] * r;
}

// ---------------- K5: partial PV: part[b,c,q,n] = sum_{k in chunk} V[b,k,n]*s[b,k,q]
__global__ __launch_bounds__(128) void k_pv(
    const float* __restrict__ values, const float* __restrict__ sc,
    float* __restrict__ part)
{
  __shared__ float s_sc[64 * 16];
  const int c = blockIdx.x, b = blockIdx.y;   // 32 chunks of 64 k
  const int tid = threadIdx.x;
  const float* ssrc = sc + (b * 2048 + c * 64) * 16;
  #pragma unroll
  for (int i = 0; i < 2; ++i)
    *(float4*)&s_sc[tid * 4 + i * 512] = *(const float4*)&ssrc[tid * 4 + i * 512];
  __syncthreads();

  float4 acc[16];
  #pragma unroll
  for (int q = 0; q < 16; ++q) acc[q] = make_float4(0.f, 0.f, 0.f, 0.f);

  const float* vbase = values + ((size_t)(b * 2048 + c * 64)) * 512 + tid * 4;
  #pragma unroll 2
  for (int kk = 0; kk < 64; ++kk) {
    const float4 v4 = *(const float4*)(vbase + (size_t)kk * 512);
    #pragma unroll
    for (int g = 0; g < 4; ++g) {
      const float4 s4 = *(const float4*)&s_sc[kk * 16 + g * 4];
      #define PV_ACC(qi, sv) { float4& a = acc[qi]; a.x += v4.x*(sv); a.y += v4.y*(sv); a.z += v4.z*(sv); a.w += v4.w*(sv); }
      PV_ACC(g*4+0, s4.x); PV_ACC(g*4+1, s4.y); PV_ACC(g*4+2, s4.z); PV_ACC(g*4+3, s4.w);
      #undef PV_ACC
    }
  }
  float* pbase = part + ((size_t)((b * 32 + c) * 16)) * 512 + tid * 4;
  #pragma unroll
  for (int q = 0; q < 16; ++q) *(float4*)(pbase + q * 512) = acc[q];
}

// ---------------- K6: reduce 32 chunks -> out[b,q,n] ----------------------
__global__ __launch_bounds__(256) void k_reduce(
    const float* __restrict__ part, float* __restrict__ out)
{
  const int o = blockIdx.x * 256 + threadIdx.x;   // < 65536
  const int n = o & 511;
  const int bq = o >> 9;
  const int q = bq & 15;
  const int b = bq >> 4;
  const float* p = part + ((size_t)(b * 32 * 16 + q)) * 512 + n;
  float s = 0.f;
  #pragma unroll
  for (int c2 = 0; c2 < 32; ++c2) s += p[(size_t)c2 * 16 * 512];
  out[o] = s;
}

extern "C" void kernel_launch(void* const* d_in, const int* in_sizes, int n_in,
                              void* d_out, int out_size, void* d_ws, size_t ws_size,
                              hipStream_t stream)
{
  const float* query  = (const float*)d_in[0];
  const float* keys   = (const float*)d_in[1];
  const float* values = (const float*)d_in[2];
  const float* W      = (const float*)d_in[3];
  const float* w_bias = (const float*)d_in[4];
  const float* vw     = (const float*)d_in[5];
  // d_in[6] (v_bias) is a constant shift of all logits -> softmax-invariant, unused.

  char* ws = (char*)d_ws;
  unsigned short* keys_bf  = (unsigned short*)(ws + OFF_KEYS_BF);
  unsigned short* query_bf = (unsigned short*)(ws + OFF_QUERY_BF);
  unsigned short* wk_bf    = (unsigned short*)(ws + OFF_WK_BF);
  unsigned short* wq_bf    = (unsigned short*)(ws + OFF_WQ_BF);
  float* kpb  = (float*)(ws + OFF_KPB);
  float* qp   = (float*)(ws + OFF_QP);
  float* e    = (float*)(ws + OFF_E);
  float* part = (float*)(ws + OFF_PART);

  hipLaunchKernelGGL(k_convert, dim3(4384), dim3(256), 0, stream,
                     query, keys, W, keys_bf, query_bf, wk_bf, wq_bf);
  hipLaunchKernelGGL(k_gemm, dim3(4, 129), dim3(256), 0, stream,
                     keys_bf, query_bf, wk_bf, wq_bf, w_bias, kpb, qp);
  hipLaunchKernelGGL(k_energy, dim3(4096), dim3(256), 0, stream, kpb, qp, vw, e);
  hipLaunchKernelGGL(k_softmax, dim3(128), dim3(256), 0, stream, e);
  hipLaunchKernelGGL(k_pv, dim3(32, 8), dim3(128), 0, stream, values, e, part);
  hipLaunchKernelGGL(k_reduce, dim3(256), dim3(256), 0, stream, part, (float*)d_out);
}

// Round 2
// 96.621 us; speedup vs baseline: 1.1387x; 1.1387x over previous
//
#include <hip/hip_runtime.h>
#include <cstddef>

using bf16x8  = __attribute__((ext_vector_type(8))) short;
using f32x4   = __attribute__((ext_vector_type(4))) float;
using ushort8 = __attribute__((ext_vector_type(8))) unsigned short;

#define GLL16(gp, lp) __builtin_amdgcn_global_load_lds( \
    (const __attribute__((address_space(1))) unsigned int*)(const void*)(gp), \
    (__attribute__((address_space(3))) unsigned int*)(void*)(lp), 16, 0, 0)

__device__ __forceinline__ float exp2_f(float x){ float r; asm("v_exp_f32 %0, %1" : "=v"(r) : "v"(x)); return r; }
__device__ __forceinline__ float rcp_f (float x){ float r; asm("v_rcp_f32 %0, %1" : "=v"(r) : "v"(x)); return r; }

__device__ __forceinline__ unsigned short f2bf(float f){
  unsigned int u = __float_as_uint(f);
  u = u + 0x7FFFu + ((u >> 16) & 1u);
  return (unsigned short)(u >> 16);
}

// problem sizes: B=8 Q=16 KV=2048 NQ=NK=NV=H=512
#define KEYS_N   8388608
#define QUERY_N  65536
#define SCALE_2LOG2E 2.885390081777927f   // 2*log2(e): exp2(x*S) = exp(2x)

// workspace layout (bytes); total = 61,210,624 (unchanged from round 1)
// e_part (4MB) aliases keys_bf region: keys_bf dead after k_gemm.
#define OFF_EPART     0u          // 4 x [8][2048][16] f32 partial logits
#define OFF_KEYS_BF   0u          // 16384x512 bf16 (dead after gemm)
#define OFF_QUERY_BF  16777216u   // 128x512 bf16
#define OFF_WK_BF     16908288u   // 512x512 bf16
#define OFF_WQ_BF     17432576u   // 512x512 bf16
#define OFF_EKB       17956864u   // 16384x512 f32: exp2(S*(k_part+bias))
#define OFF_EQB       51511296u   // 128x512 f32:   exp2(S*q_part)
#define OFF_SC        51773440u   // 8x2048x16 f32 scores
#define OFF_PART      52822016u   // 8x32x16x512 f32 partial outputs

// ---------------- K1: f32 -> bf16 conversion (keys, query, W split) -------
__global__ __launch_bounds__(256) void k_convert(
    const float* __restrict__ query, const float* __restrict__ keys,
    const float* __restrict__ W,
    unsigned short* __restrict__ keys_bf, unsigned short* __restrict__ query_bf,
    unsigned short* __restrict__ wk_bf, unsigned short* __restrict__ wq_bf)
{
  int idx = (blockIdx.x * 256 + threadIdx.x) * 8;
  const float* src;
  unsigned short* dst;
  if (idx < KEYS_N) { src = keys + idx; dst = keys_bf + idx; }
  else if (idx < KEYS_N + QUERY_N) { int e = idx - KEYS_N; src = query + e; dst = query_bf + e; }
  else {
    int e = idx - (KEYS_N + QUERY_N);
    int h = e >> 10, c = e & 1023;             // W row-major [512][1024]
    src = W + e;
    dst = (c < 512) ? (wq_bf + h * 512 + c) : (wk_bf + h * 512 + (c - 512));
  }
  float4 a = *(const float4*)src;
  float4 b = *(const float4*)(src + 4);
  ushort8 o;
  o[0]=f2bf(a.x); o[1]=f2bf(a.y); o[2]=f2bf(a.z); o[3]=f2bf(a.w);
  o[4]=f2bf(b.x); o[5]=f2bf(b.y); o[6]=f2bf(b.z); o[7]=f2bf(b.w);
  *(ushort8*)dst = o;
}

// ---------------- K2: MFMA GEMM -> ekb = exp2(S*(keys·Wk^T + bias)), eqb = exp2(S*query·Wq^T)
__global__ __launch_bounds__(256) void k_gemm(
    const unsigned short* __restrict__ keys_bf, const unsigned short* __restrict__ query_bf,
    const unsigned short* __restrict__ wk_bf, const unsigned short* __restrict__ wq_bf,
    const float* __restrict__ w_bias,
    float* __restrict__ ekb, float* __restrict__ eqb)
{
  __shared__ short As[2][128 * 64];
  __shared__ short Bs[2][128 * 64];

  const int tid = threadIdx.x;
  const int l = tid & 63;
  const int w = tid >> 6;
  const int by = blockIdx.y;            // 0..128; 128 => query tile
  const bool isq = (by == 128);
  const int n0 = blockIdx.x * 128;

  const unsigned short* Aptr = isq ? query_bf : (keys_bf + (size_t)by * 128 * 512);
  const unsigned short* Bptr = (isq ? wq_bf : wk_bf) + (size_t)n0 * 512;

  const int eo_base = w * 2048 + l * 8;   // element offset in 128x64 tile

  f32x4 acc[4][4];
  #pragma unroll
  for (int i = 0; i < 4; ++i)
    #pragma unroll
    for (int j = 0; j < 4; ++j)
      acc[i][j] = (f32x4){0.f, 0.f, 0.f, 0.f};

  auto stage = [&](int buf, int kt) {
    const int k0 = kt * 64;
    #pragma unroll
    for (int r = 0; r < 4; ++r) {
      const int eo = eo_base + r * 512;
      const int row = eo >> 6;
      const int col = eo & 63;
      GLL16(Aptr + row * 512 + k0 + col, &As[buf][w * 2048 + r * 512]);
      GLL16(Bptr + row * 512 + k0 + col, &Bs[buf][w * 2048 + r * 512]);
    }
  };

  const int wm = w >> 1, wn = w & 1;
  const int fr = l & 15;          // m/n index within 16x16 fragment
  const int fg = l >> 4;          // k-group

  auto compute = [&](int buf) {
    #pragma unroll
    for (int ks = 0; ks < 2; ++ks) {
      bf16x8 af[4], bfv[4];
      #pragma unroll
      for (int i = 0; i < 4; ++i) {
        const int ar = wm * 64 + i * 16 + fr;
        af[i]  = *(const bf16x8*)&As[buf][ar * 64 + ks * 32 + fg * 8];
        const int br = wn * 64 + i * 16 + fr;
        bfv[i] = *(const bf16x8*)&Bs[buf][br * 64 + ks * 32 + fg * 8];
      }
      #pragma unroll
      for (int i = 0; i < 4; ++i)
        #pragma unroll
        for (int j = 0; j < 4; ++j)
          acc[i][j] = __builtin_amdgcn_mfma_f32_16x16x32_bf16(af[i], bfv[j], acc[i][j], 0, 0, 0);
    }
  };

  stage(0, 0);
  for (int kt = 0; kt < 8; ++kt) {
    __syncthreads();
    if (kt < 7) stage((kt + 1) & 1, kt + 1);
    compute(kt & 1);
  }

  // epilogue: C/D layout col=lane&15, row=(lane>>4)*4+reg; write exp2 of scaled value
  #pragma unroll
  for (int j = 0; j < 4; ++j) {
    const int gh = n0 + wn * 64 + j * 16 + fr;
    const float bias = isq ? 0.f : w_bias[gh];
    #pragma unroll
    for (int i = 0; i < 4; ++i) {
      #pragma unroll
      for (int r = 0; r < 4; ++r) {
        const int gm = wm * 64 + i * 16 + fg * 4 + r;
        const float ev = exp2_f((acc[i][j][r] + bias) * SCALE_2LOG2E);
        if (isq) eqb[gm * 512 + gh] = ev;
        else     ekb[((size_t)by * 128 + gm) * 512 + gh] = ev;
      }
    }
  }
}

// ---------------- K3: partial logits via t = 1/(1 + ek*eq) ----------------
// e_part[hc][b][k][q] = sum_{h in chunk} v_h / (1 + ek[b,k,h]*eq[b,q,h]) * (-2)
// wave: 16 k-rows x 16 q x 128 h. ek,v in regs (reused across q); eq in LDS.
__global__ __launch_bounds__(256) void k_energy(
    const float* __restrict__ ekb, const float* __restrict__ eqb,
    const float* __restrict__ vw, float* __restrict__ e_part)
{
  __shared__ float eqs[16 * 128];
  const int tid = threadIdx.x;
  const int bid = blockIdx.x;               // 1024 = 8b x 32ktg x 4hc
  const int hc = bid & 3;
  const int ktg = (bid >> 2) & 31;
  const int b = bid >> 7;
  const int h0 = hc * 128;

  // stage eq chunk [16 q][128 h]
  {
    const int q = tid >> 4, c0 = (tid & 15) * 8;
    const float* src = eqb + (size_t)(b * 16 + q) * 512 + h0 + c0;
    *(float4*)&eqs[q * 128 + c0]     = *(const float4*)src;
    *(float4*)&eqs[q * 128 + c0 + 4] = *(const float4*)(src + 4);
  }

  const int w = tid >> 6, l = tid & 63;
  const int kt = ktg * 4 + w;
  const int g = l & 3, kl = l >> 2;
  const int k = kt * 16 + kl;

  // ek (32 regs) and v (32 regs); lane owns h-cols {s*32 + g*4 + j, s*32 + 16 + g*4 + j}
  float ek[32], vv[32];
  const float* ekrow = ekb + ((size_t)(b * 2048 + k)) * 512 + h0;
  #pragma unroll
  for (int s = 0; s < 4; ++s) {
    *(float4*)&ek[s * 8]     = *(const float4*)(ekrow + s * 32 + g * 4);
    *(float4*)&ek[s * 8 + 4] = *(const float4*)(ekrow + s * 32 + 16 + g * 4);
    *(float4*)&vv[s * 8]     = *(const float4*)(vw + h0 + s * 32 + g * 4);
    *(float4*)&vv[s * 8 + 4] = *(const float4*)(vw + h0 + s * 32 + 16 + g * 4);
  }
  __syncthreads();

  const size_t epbase = (size_t)hc * 262144 + ((size_t)(b * 2048 + k)) * 16;

  #pragma unroll 2
  for (int q = 0; q < 16; ++q) {
    float a0 = 0.f, a1 = 0.f;
    #pragma unroll
    for (int s = 0; s < 4; ++s) {
      const float* er = &eqs[q * 128 + s * 32 + g * 4];
      const float4 E0 = *(const float4*)er;
      const float4 E1 = *(const float4*)(er + 16);
      a0 = fmaf(vv[s*8+0], rcp_f(fmaf(ek[s*8+0], E0.x, 1.f)), a0);
      a1 = fmaf(vv[s*8+1], rcp_f(fmaf(ek[s*8+1], E0.y, 1.f)), a1);
      a0 = fmaf(vv[s*8+2], rcp_f(fmaf(ek[s*8+2], E0.z, 1.f)), a0);
      a1 = fmaf(vv[s*8+3], rcp_f(fmaf(ek[s*8+3], E0.w, 1.f)), a1);
      a0 = fmaf(vv[s*8+4], rcp_f(fmaf(ek[s*8+4], E1.x, 1.f)), a0);
      a1 = fmaf(vv[s*8+5], rcp_f(fmaf(ek[s*8+5], E1.y, 1.f)), a1);
      a0 = fmaf(vv[s*8+6], rcp_f(fmaf(ek[s*8+6], E1.z, 1.f)), a0);
      a1 = fmaf(vv[s*8+7], rcp_f(fmaf(ek[s*8+7], E1.w, 1.f)), a1);
    }
    float a = a0 + a1;
    a += __shfl_xor(a, 1, 64);   // reduce over g (lanes share l>>2)
    a += __shfl_xor(a, 2, 64);
    if (g == 0) e_part[epbase + q] = -2.f * a;
  }
}

// ---------------- K4: softmax over k: sum 4 partials, normalize -----------
__global__ __launch_bounds__(256) void k_softmax(
    const float* __restrict__ e_part, float* __restrict__ sc)
{
  const int b = blockIdx.x >> 4, q = blockIdx.x & 15;
  const int base = b * 32768 + q;           // stride 16 over k
  const int tid = threadIdx.x;
  __shared__ float redm[4], reds[4];

  float vals[8];
  float mx = -1e30f;
  #pragma unroll
  for (int i = 0; i < 8; ++i) {
    const int x = base + (tid + i * 256) * 16;
    vals[i] = (e_part[x] + e_part[x + 262144]) + (e_part[x + 524288] + e_part[x + 786432]);
    mx = fmaxf(mx, vals[i]);
  }
  #pragma unroll
  for (int msk = 1; msk < 64; msk <<= 1) mx = fmaxf(mx, __shfl_xor(mx, msk, 64));
  if ((tid & 63) == 0) redm[tid >> 6] = mx;
  __syncthreads();
  mx = fmaxf(fmaxf(redm[0], redm[1]), fmaxf(redm[2], redm[3]));

  float ex[8], sum = 0.f;
  #pragma unroll
  for (int i = 0; i < 8; ++i) { ex[i] = __expf(vals[i] - mx); sum += ex[i]; }
  #pragma unroll
  for (int msk = 1; msk < 64; msk <<= 1) sum += __shfl_xor(sum, msk, 64);
  if ((tid & 63) == 0) reds[tid >> 6] = sum;
  __syncthreads();
  sum = reds[0] + reds[1] + reds[2] + reds[3];
  const float r = 1.f / sum;
  #pragma unroll
  for (int i = 0; i < 8; ++i) sc[base + (tid + i * 256) * 16] = ex[i] * r;
}

// ---------------- K5: partial PV: part[b,c,q,n] = sum_{k in chunk} V[b,k,n]*s[b,k,q]
__global__ __launch_bounds__(128) void k_pv(
    const float* __restrict__ values, const float* __restrict__ sc,
    float* __restrict__ part)
{
  __shared__ float s_sc[64 * 16];
  const int c = blockIdx.x, b = blockIdx.y;   // 32 chunks of 64 k
  const int tid = threadIdx.x;
  const float* ssrc = sc + (b * 2048 + c * 64) * 16;
  #pragma unroll
  for (int i = 0; i < 2; ++i)
    *(float4*)&s_sc[tid * 4 + i * 512] = *(const float4*)&ssrc[tid * 4 + i * 512];
  __syncthreads();

  float4 acc[16];
  #pragma unroll
  for (int q = 0; q < 16; ++q) acc[q] = make_float4(0.f, 0.f, 0.f, 0.f);

  const float* vbase = values + ((size_t)(b * 2048 + c * 64)) * 512 + tid * 4;
  #pragma unroll 2
  for (int kk = 0; kk < 64; ++kk) {
    const float4 v4 = *(const float4*)(vbase + (size_t)kk * 512);
    #pragma unroll
    for (int g = 0; g < 4; ++g) {
      const float4 s4 = *(const float4*)&s_sc[kk * 16 + g * 4];
      #define PV_ACC(qi, sv) { float4& a = acc[qi]; a.x += v4.x*(sv); a.y += v4.y*(sv); a.z += v4.z*(sv); a.w += v4.w*(sv); }
      PV_ACC(g*4+0, s4.x); PV_ACC(g*4+1, s4.y); PV_ACC(g*4+2, s4.z); PV_ACC(g*4+3, s4.w);
      #undef PV_ACC
    }
  }
  float* pbase = part + ((size_t)((b * 32 + c) * 16)) * 512 + tid * 4;
  #pragma unroll
  for (int q = 0; q < 16; ++q) *(float4*)(pbase + q * 512) = acc[q];
}

// ---------------- K6: reduce 32 chunks -> out[b,q,n] ----------------------
__global__ __launch_bounds__(256) void k_reduce(
    const float* __restrict__ part, float* __restrict__ out)
{
  const int o = blockIdx.x * 256 + threadIdx.x;   // < 65536
  const int n = o & 511;
  const int bq = o >> 9;
  const int q = bq & 15;
  const int b = bq >> 4;
  const float* p = part + ((size_t)(b * 32 * 16 + q)) * 512 + n;
  float s = 0.f;
  #pragma unroll
  for (int c2 = 0; c2 < 32; ++c2) s += p[(size_t)c2 * 16 * 512];
  out[o] = s;
}

extern "C" void kernel_launch(void* const* d_in, const int* in_sizes, int n_in,
                              void* d_out, int out_size, void* d_ws, size_t ws_size,
                              hipStream_t stream)
{
  const float* query  = (const float*)d_in[0];
  const float* keys   = (const float*)d_in[1];
  const float* values = (const float*)d_in[2];
  const float* W      = (const float*)d_in[3];
  const float* w_bias = (const float*)d_in[4];
  const float* vw     = (const float*)d_in[5];
  // d_in[6] (v_bias) + sum_h v_h are (k)-constant logit shifts -> softmax-invariant.

  char* ws = (char*)d_ws;
  unsigned short* keys_bf  = (unsigned short*)(ws + OFF_KEYS_BF);
  unsigned short* query_bf = (unsigned short*)(ws + OFF_QUERY_BF);
  unsigned short* wk_bf    = (unsigned short*)(ws + OFF_WK_BF);
  unsigned short* wq_bf    = (unsigned short*)(ws + OFF_WQ_BF);
  float* ekb    = (float*)(ws + OFF_EKB);
  float* eqb    = (float*)(ws + OFF_EQB);
  float* e_part = (float*)(ws + OFF_EPART);   // aliases keys_bf (dead after gemm)
  float* sc     = (float*)(ws + OFF_SC);
  float* part   = (float*)(ws + OFF_PART);

  hipLaunchKernelGGL(k_convert, dim3(4384), dim3(256), 0, stream,
                     query, keys, W, keys_bf, query_bf, wk_bf, wq_bf);
  hipLaunchKernelGGL(k_gemm, dim3(4, 129), dim3(256), 0, stream,
                     keys_bf, query_bf, wk_bf, wq_bf, w_bias, ekb, eqb);
  hipLaunchKernelGGL(k_energy, dim3(1024), dim3(256), 0, stream, ekb, eqb, vw, e_part);
  hipLaunchKernelGGL(k_softmax, dim3(128), dim3(256), 0, stream, e_part, sc);
  hipLaunchKernelGGL(k_pv, dim3(32, 8), dim3(128), 0, stream, values, sc, part);
  hipLaunchKernelGGL(k_reduce, dim3(256), dim3(256), 0, stream, part, (float*)d_out);
}